// Round 7
// baseline (167.021 us; speedup 1.0000x reference)
//
#include <hip/hip_runtime.h>
#include <hip/hip_cooperative_groups.h>
#include <math.h>

namespace cg = cooperative_groups;

#define N 128
#define HID 512
#define NH (N * HID)                 // 65536
#define SNH ((size_t)N * NH)         // 8388608 elements per s
#define NPAIRS (N * (N + 1) / 2)     // 8256

// workspace layout (float offsets)
#define OFF_SA 0
#define OFF_SB 131072
#define OFF_DG 262144
#define OFF_XR 393216
#define OFF_YC 524288
#define OFF_SV 655360
#define OFF_DB 656384

typedef float vf4 __attribute__((ext_vector_type(4)));
union F4 { vf4 v; float f[4]; };

// ---------------------------------------------------------------------------
// P1: one block per (s, idx, pass). 512 virtual blocks.
//   pass 0: Sa[s][idx][h] = sum_a x[s][a][idx][h]   (column of M)
//   pass 1: Sb[s][idx][h] = sum_b x[s][idx][b][h]   (row) + Dg
// 512 threads = 128 hg x 4 q; q sums 32 indices with 4 independent accs.
// ---------------------------------------------------------------------------
__device__ __forceinline__ void phase1(int u, int tid, const float* __restrict__ x,
                                       float* __restrict__ Sa, float* __restrict__ Sb,
                                       float* __restrict__ Dg) {
    const int pass = u & 1;
    const int idx  = (u >> 1) & 127;
    const int s    = u >> 8;
    const int hg   = tid & 127;
    const int q    = tid >> 7;            // 0..3
    const int hoff = hg * 4;

    const float* xs = x + (size_t)s * SNH;

    __shared__ F4 red[4][128];            // 8 KiB

    F4 a0, a1, a2, a3;
    a0.v = (vf4)(0.f); a1.v = (vf4)(0.f); a2.v = (vf4)(0.f); a3.v = (vf4)(0.f);
    F4 dv; dv.v = (vf4)(0.f);

    if (pass == 0) {
        const float* p = xs + (size_t)(q * 32) * NH + idx * HID + hoff;
        for (int a = 0; a < 32; a += 4) {
            F4 v0; v0.v = *reinterpret_cast<const vf4*>(p + (size_t)(a + 0) * NH);
            F4 v1; v1.v = *reinterpret_cast<const vf4*>(p + (size_t)(a + 1) * NH);
            F4 v2; v2.v = *reinterpret_cast<const vf4*>(p + (size_t)(a + 2) * NH);
            F4 v3; v3.v = *reinterpret_cast<const vf4*>(p + (size_t)(a + 3) * NH);
            a0.v += v0.v; a1.v += v1.v; a2.v += v2.v; a3.v += v3.v;
        }
    } else {
        const float* p = xs + (size_t)idx * NH + (q * 32) * HID + hoff;
        for (int b = 0; b < 32; b += 4) {
            F4 v0; v0.v = *reinterpret_cast<const vf4*>(p + (b + 0) * HID);
            F4 v1; v1.v = *reinterpret_cast<const vf4*>(p + (b + 1) * HID);
            F4 v2; v2.v = *reinterpret_cast<const vf4*>(p + (b + 2) * HID);
            F4 v3; v3.v = *reinterpret_cast<const vf4*>(p + (b + 3) * HID);
            a0.v += v0.v; a1.v += v1.v; a2.v += v2.v; a3.v += v3.v;
        }
        if (q == 0)
            dv.v = *reinterpret_cast<const vf4*>(xs + (size_t)idx * NH + idx * HID + hoff);
    }
    a0.v = (a0.v + a1.v) + (a2.v + a3.v);
    red[q][hg] = a0;
    __syncthreads();

    if (q == 0) {
        F4 t;
        t.v = (red[0][hg].v + red[1][hg].v) + (red[2][hg].v + red[3][hg].v);
        float* dst = (pass == 0 ? Sa : Sb) + ((size_t)s * N + idx) * HID + hoff;
        *reinterpret_cast<vf4*>(dst) = t.v;
        if (pass == 1)
            *reinterpret_cast<vf4*>(Dg + ((size_t)s * N + idx) * HID + hoff) = dv.v;
    }
    __syncthreads();   // red reused safety if inlined twice
}

// ---------------------------------------------------------------------------
// P2: per-(s,h) statistics on 32 virtual blocks x 512 threads.
// ---------------------------------------------------------------------------
__device__ __forceinline__ void phase2(int bi, int tid,
                                       const float* __restrict__ Sa,
                                       const float* __restrict__ Sb,
                                       const float* __restrict__ Dg,
                                       float* __restrict__ Xr, float* __restrict__ Yc,
                                       float* __restrict__ Sv, float* __restrict__ Db) {
    const int s   = bi >> 4;
    const int hc  = bi & 15;
    const int iq  = tid >> 5;             // 0..15
    const int hl  = tid & 31;
    const int h   = hc * 32 + hl;
    const size_t base = (size_t)s * N * HID;

    float T = 0.f, D = 0.f;
    #pragma unroll
    for (int i = iq; i < N; i += 16) {
        T += Sa[base + (size_t)i * HID + h];
        D += Dg[base + (size_t)i * HID + h];
    }

    __shared__ float redT[16][32];
    __shared__ float redD[16][32];
    __shared__ float shS[32];
    redT[iq][hl] = T;
    redD[iq][hl] = D;
    __syncthreads();
    if (iq == 0) {
        float Tt = 0.f, Dd = 0.f;
        #pragma unroll
        for (int q = 0; q < 16; ++q) { Tt += redT[q][hl]; Dd += redD[q][hl]; }
        const float sh   = (Tt - Dd) * (1.0f / 16256.0f);   // /(n(n-1))
        const float dbar = Dd * (1.0f / 128.0f);
        Sv[s * HID + h] = sh;
        Db[s * HID + h] = dbar;
        shS[hl] = sh;
    }
    __syncthreads();

    const float sh    = shS[hl];
    const float k127s = 127.0f * sh;
    const float inv   = 1.0f / 16128.0f;  // 1/(n(n-2))
    #pragma unroll
    for (int i = iq; i < N; i += 16) {
        const size_t o = base + (size_t)i * HID + h;
        const float d = Dg[o];
        const float r = Sa[o] - d - k127s;
        const float c = Sb[o] - d - k127s;
        Xr[o] = (127.0f * r + c) * inv;
        Yc[o] = (127.0f * c + r) * inv;
    }
}

// ---------------------------------------------------------------------------
// P3: output over triangular pairs. 512 blocks x 4 slots x 9 iters.
// ---------------------------------------------------------------------------
__device__ __forceinline__ void phase3(int bi, int tid,
                                       const float* __restrict__ x,
                                       const float* __restrict__ w,
                                       const float* __restrict__ iso,
                                       const float* __restrict__ Xr,
                                       const float* __restrict__ Yc,
                                       const float* __restrict__ Sv,
                                       const float* __restrict__ Db,
                                       float* __restrict__ out) {
    const int k  = tid >> 7;              // pair slot 0..3
    const int ht = tid & 127;
    const int hoff = ht * 4;

    float c[7];
    #pragma unroll
    for (int j = 0; j < 7; ++j) {
        float acc = 0.f;
        #pragma unroll
        for (int i = 0; i < 7; ++i) acc += w[i * 7 + j] * iso[i * 7 + j];
        c[j] = acc;
    }
    const float c1 = c[0], c2 = c[1], c3 = c[2], c4 = c[3], c5 = c[4];
    const float al = 0.5f * (c[5] + c[6]);
    const float be = 0.5f * (c[5] - c[6]);

    #define TRI_OFF(aa) ((aa) * N - (((aa) * ((aa) - 1)) >> 1))
    for (int it = 0; it < 9; ++it) {
        const int pg = it * 2048 + bi * 4 + k;
        if (pg >= 2 * NPAIRS) break;
        const int s  = (pg >= NPAIRS) ? 1 : 0;
        const int p  = pg - s * NPAIRS;

        int a = (int)((257.0f - sqrtf((float)(66049 - 8 * p))) * 0.5f);
        if (a < 0) a = 0;
        if (a > N - 1) a = N - 1;
        while (a > 0 && TRI_OFF(a) > p) --a;
        while (TRI_OFF(a + 1) <= p) ++a;
        const int b = a + (p - TRI_OFF(a));

        const size_t sbase    = (size_t)s * SNH;
        const size_t statbase = (size_t)s * N * HID;

        if (a == b) {
            F4 v;  v.v  = *reinterpret_cast<const vf4*>(x + sbase + ((size_t)a * N + a) * HID + hoff);
            F4 db; db.v = *reinterpret_cast<const vf4*>(Db + (size_t)s * HID + hoff);
            F4 o;
            #pragma unroll
            for (int j = 0; j < 4; ++j)
                o.f[j] = c1 * db.f[j] + c2 * (v.f[j] - db.f[j]);
            __builtin_nontemporal_store(o.v,
                reinterpret_cast<vf4*>(out + sbase + ((size_t)a * N + a) * HID + hoff));
            continue;
        }

        F4 va;  va.v  = *reinterpret_cast<const vf4*>(x + sbase + ((size_t)a * N + b) * HID + hoff);
        F4 vb;  vb.v  = *reinterpret_cast<const vf4*>(x + sbase + ((size_t)b * N + a) * HID + hoff);
        F4 xra; xra.v = *reinterpret_cast<const vf4*>(Xr + statbase + (size_t)a * HID + hoff);
        F4 xrb; xrb.v = *reinterpret_cast<const vf4*>(Xr + statbase + (size_t)b * HID + hoff);
        F4 yca; yca.v = *reinterpret_cast<const vf4*>(Yc + statbase + (size_t)a * HID + hoff);
        F4 ycb; ycb.v = *reinterpret_cast<const vf4*>(Yc + statbase + (size_t)b * HID + hoff);
        F4 sh;  sh.v  = *reinterpret_cast<const vf4*>(Sv + (size_t)s * HID + hoff);

        F4 oab, oba;
        #pragma unroll
        for (int j = 0; j < 4; ++j) {
            const float U = va.f[j] - sh.f[j] - xrb.f[j] - yca.f[j];
            const float V = vb.f[j] - sh.f[j] - xra.f[j] - ycb.f[j];
            oab.f[j] = c3 * sh.f[j] + c4 * xrb.f[j] + c5 * yca.f[j] + al * U + be * V;
            oba.f[j] = c3 * sh.f[j] + c4 * xra.f[j] + c5 * ycb.f[j] + al * V + be * U;
        }
        __builtin_nontemporal_store(oab.v,
            reinterpret_cast<vf4*>(out + sbase + ((size_t)a * N + b) * HID + hoff));
        __builtin_nontemporal_store(oba.v,
            reinterpret_cast<vf4*>(out + sbase + ((size_t)b * N + a) * HID + hoff));
    }
}

// ---------------------------------------------------------------------------
// Fused cooperative kernel: 512 blocks x 512 threads, 2 grid syncs.
// __launch_bounds__(512,4): VGPR cap 128 -> 2 blocks/CU -> 1024 capacity.
// ---------------------------------------------------------------------------
__global__ __launch_bounds__(512, 4)
void schur_fused(const float* __restrict__ x, const float* __restrict__ w,
                 const float* __restrict__ iso,
                 float* __restrict__ Sa, float* __restrict__ Sb,
                 float* __restrict__ Dg,
                 float* __restrict__ Xr, float* __restrict__ Yc,
                 float* __restrict__ Sv, float* __restrict__ Db,
                 float* __restrict__ out) {
    phase1(blockIdx.x, threadIdx.x, x, Sa, Sb, Dg);
    cg::this_grid().sync();
    if (blockIdx.x < 32)
        phase2(blockIdx.x, threadIdx.x, Sa, Sb, Dg, Xr, Yc, Sv, Db);
    cg::this_grid().sync();
    phase3(blockIdx.x, threadIdx.x, x, w, iso, Xr, Yc, Sv, Db, out);
}

// ---------------------------------------------------------------------------
// Fallback: same phases as 3 plain kernels.
// ---------------------------------------------------------------------------
__global__ __launch_bounds__(512, 4)
void k_p1(const float* __restrict__ x, float* __restrict__ Sa,
          float* __restrict__ Sb, float* __restrict__ Dg) {
    phase1(blockIdx.x, threadIdx.x, x, Sa, Sb, Dg);
}
__global__ __launch_bounds__(512)
void k_p2(const float* __restrict__ Sa, const float* __restrict__ Sb,
          const float* __restrict__ Dg,
          float* __restrict__ Xr, float* __restrict__ Yc,
          float* __restrict__ Sv, float* __restrict__ Db) {
    phase2(blockIdx.x, threadIdx.x, Sa, Sb, Dg, Xr, Yc, Sv, Db);
}
__global__ __launch_bounds__(512, 4)
void k_p3(const float* __restrict__ x, const float* __restrict__ w,
          const float* __restrict__ iso,
          const float* __restrict__ Xr, const float* __restrict__ Yc,
          const float* __restrict__ Sv, const float* __restrict__ Db,
          float* __restrict__ out) {
    phase3(blockIdx.x, threadIdx.x, x, w, iso, Xr, Yc, Sv, Db, out);
}

extern "C" void kernel_launch(void* const* d_in, const int* in_sizes, int n_in,
                              void* d_out, int out_size, void* d_ws, size_t ws_size,
                              hipStream_t stream) {
    const float* x   = (const float*)d_in[0];
    const float* w   = (const float*)d_in[1];
    const float* iso = (const float*)d_in[2];
    float* out = (float*)d_out;
    float* ws  = (float*)d_ws;

    float* Sa = ws + OFF_SA;
    float* Sb = ws + OFF_SB;
    float* Dg = ws + OFF_DG;
    float* Xr = ws + OFF_XR;
    float* Yc = ws + OFF_YC;
    float* Sv = ws + OFF_SV;
    float* Db = ws + OFF_DB;

    void* args[] = {
        (void*)&x, (void*)&w, (void*)&iso,
        (void*)&Sa, (void*)&Sb, (void*)&Dg,
        (void*)&Xr, (void*)&Yc, (void*)&Sv, (void*)&Db,
        (void*)&out
    };
    hipError_t e = hipLaunchCooperativeKernel((void*)schur_fused, dim3(512), dim3(512),
                                              args, 0, stream);
    if (e != hipSuccess) {
        // deterministic fallback: same phases, 3 launches
        k_p1<<<512, 512, 0, stream>>>(x, Sa, Sb, Dg);
        k_p2<<<32, 512, 0, stream>>>(Sa, Sb, Dg, Xr, Yc, Sv, Db);
        k_p3<<<512, 512, 0, stream>>>(x, w, iso, Xr, Yc, Sv, Db, out);
    }
}